// Round 4
// baseline (394.703 us; speedup 1.0000x reference)
//
#include <hip/hip_runtime.h>
#include <hip/hip_bf16.h>

#define N_NODES   100000
#define N_EDGES   800000
#define NODE_DIM  64
#define EDGE_DIM  64
#define GEO_DIM   8
#define GEO_OUT   32
#define COND_DIM  512
#define N_GRAPHS  64

typedef short  bf8   __attribute__((ext_vector_type(8)));   // 8 bf16 in 4 VGPRs
typedef float  f32x4 __attribute__((ext_vector_type(4)));
typedef unsigned short u16x8 __attribute__((ext_vector_type(8)));

__device__ __forceinline__ float b2f(unsigned short u) {
    return __uint_as_float(((unsigned)u) << 16);
}
__device__ __forceinline__ short f2b(float f) {   // round-to-nearest-even f32->bf16
    unsigned u = __float_as_uint(f);
    u = (u + 0x7FFFu + ((u >> 16) & 1u)) >> 16;
    return (short)u;
}
__device__ __forceinline__ unsigned f2b2(float lo, float hi) {  // packed RNE pair
    __hip_bfloat162 h = __float22bfloat162_rn(make_float2(lo, hi));
    union { __hip_bfloat162 h; unsigned u; } cv;
    cv.h = h;
    return cv.u;
}
__device__ __forceinline__ float rdlane(float v, int l) {
    return __int_as_float(__builtin_amdgcn_readlane(__float_as_int(v), l));
}

// ---------------------------------------------------------------------------
// prep+nproj merged (independent work, one launch):
//   blocks 0..63   : gamma/beta2 per graph (FiLM fold incl. geo-bias fold)
//   block  64      : Bfrag - folded 96x64 weight (Wx ; Wg@Wx_geo ; 0) in
//                    MFMA fragment order: idx = ((c*4+t)*64 + lane)*8 + j
//                    holding W[k=c*32+(lane>>4)*8+j][n=t*16+(lane&15)]
//   blocks 65..    : nproj  n_projb[n][j] = bf16(node_feats[n]@Wn[:,j]+bn[j])
// ---------------------------------------------------------------------------
__global__ __launch_bounds__(256) void prep_nproj_kernel(
        const float* __restrict__ cond, const float* __restrict__ Wc,
        const float* __restrict__ bc,   const float* __restrict__ Wg,
        const float* __restrict__ bg,   const float* __restrict__ Wx,
        const float* __restrict__ nf,   const float* __restrict__ Wn,
        const float* __restrict__ bn,
        float* __restrict__ gamma, float* __restrict__ beta2,
        unsigned short* __restrict__ Bfrag, unsigned short* __restrict__ nprojb) {
    int t = threadIdx.x;
    int g = blockIdx.x;
    if (g < N_GRAPHS) {
        __shared__ float condl[COND_DIM];
        __shared__ float gbl[128];
        for (int i = t; i < COND_DIM; i += 256) condl[i] = cond[g * COND_DIM + i];
        __syncthreads();
        if (t < 128) {
            float acc = bc[t];
            #pragma unroll 8
            for (int k = 0; k < COND_DIM; ++k) acc += condl[k] * Wc[k * 128 + t];
            gbl[t] = acc;
        }
        __syncthreads();
        if (t < 64) {
            float gam = gbl[t] + 1.0f;
            float bet = gbl[64 + t];
            float cv = 0.0f;
            #pragma unroll
            for (int i = 0; i < GEO_OUT; ++i) cv += bg[i] * Wx[(64 + i) * 64 + t];
            gamma[g * 64 + t] = gam;
            beta2[g * 64 + t] = bet + cv * gam;
        }
    } else if (g == N_GRAPHS) {
        for (int idx = t; idx < 6144; idx += 256) {
            int j    = idx & 7;
            int lane = (idx >> 3) & 63;
            int ct   = idx >> 9;
            int c    = ct >> 2, tt = ct & 3;
            int k = c * 32 + ((lane >> 4) & 3) * 8 + j;
            int n = tt * 16 + (lane & 15);
            float val;
            if (k < 64) {
                val = Wx[k * 64 + n];
            } else if (k < 72) {
                float s = 0.f;
                #pragma unroll
                for (int i = 0; i < GEO_OUT; ++i)
                    s += Wg[(k - 64) * GEO_OUT + i] * Wx[(64 + i) * 64 + n];
                val = s;
            } else {
                val = 0.f;
            }
            Bfrag[idx] = (unsigned short)f2b(val);
        }
    } else {
        int lane = t & 63;
        int wid    = (((g - N_GRAPHS - 1) << 8) + t) >> 6;
        const int nwaves = (3125 * 256) >> 6;
        float wcol[64];
        #pragma unroll
        for (int k = 0; k < 64; ++k) wcol[k] = Wn[k * 64 + lane];
        float bnl = bn[lane];
        for (int node = wid; node < N_NODES; node += nwaves) {
            float v = nf[(size_t)node * 64 + lane];
            float a0 = 0.f, a1 = 0.f, a2 = 0.f, a3 = bnl;
            #pragma unroll
            for (int k = 0; k < 64; k += 4) {
                a0 = fmaf(rdlane(v, k    ), wcol[k    ], a0);
                a1 = fmaf(rdlane(v, k + 1), wcol[k + 1], a1);
                a2 = fmaf(rdlane(v, k + 2), wcol[k + 2], a2);
                a3 = fmaf(rdlane(v, k + 3), wcol[k + 3], a3);
            }
            nprojb[(size_t)node * 64 + lane] = (unsigned short)f2b((a0 + a1) + (a2 + a3));
        }
    }
}

// ---------------------------------------------------------------------------
// edge_main: per wave, tile of 16 edges; grid-stride.
//   TRANSPOSED MFMA: mfma(Wfrag, EdgeFrag, acc) computes C^T tile-by-tile:
//   D[m][n] = C[edge=n][feat=t*16+m].  C/D layout (col=lane&15,row=q*4+reg)
//   => lane owns edge e0+(lane&15), features t*16+q*4+0..3 (float4-contig).
//   Epilogue: 1 ebatch load, float4 gamma/beta (L1-hot), float4 stores. No LDS.
// ---------------------------------------------------------------------------
__global__ __launch_bounds__(256) void edge_kernel(
        const unsigned short* __restrict__ nprojb,
        const int*   __restrict__ eidx,
        const float* __restrict__ egeo,
        const int*   __restrict__ ebatch,
        const unsigned short* __restrict__ Bfrag,
        const float* __restrict__ gamma,
        const float* __restrict__ beta2,
        float* __restrict__ out) {
    int lane = threadIdx.x & 63;
    int q  = lane >> 4;
    int mm = lane & 15;
    int wid    = (blockIdx.x * blockDim.x + threadIdx.x) >> 6;
    int nwaves = (gridDim.x * blockDim.x) >> 6;

    // W fragments, fragment-major: 12 x dwordx4
    bf8 bfrag[3][4];
    #pragma unroll
    for (int c = 0; c < 3; ++c)
        #pragma unroll
        for (int t = 0; t < 4; ++t)
            bfrag[c][t] = *(const bf8*)(Bfrag + (size_t)((c * 4 + t) * 64 + lane) * 8);

    const int NTILES = N_EDGES / 16;
    for (int tile = wid; tile < NTILES; tile += nwaves) {
        int e0 = tile * 16;
        int e  = e0 + mm;                    // this lane's edge (both frag & epilogue)
        int s = __builtin_nontemporal_load(eidx + e);
        int d = __builtin_nontemporal_load(eidx + N_EDGES + e);
        int b = __builtin_nontemporal_load(ebatch + e);   // batch id for THIS edge

        const u16x8* ps = (const u16x8*)(nprojb + (size_t)s * 64 + q * 8);
        const u16x8* pd = (const u16x8*)(nprojb + (size_t)d * 64 + q * 8);
        u16x8 s0 = ps[0], s1 = ps[4];        // k-chunk 0 (q*8..) and 1 (+32)
        u16x8 d0 = pd[0], d1 = pd[4];

        union { bf8 v; unsigned u[4]; } A0, A1, A2;
        #pragma unroll
        for (int j = 0; j < 8; j += 2) {
            A0.u[j >> 1] = f2b2(b2f(s0[j]) * b2f(d0[j]), b2f(s0[j + 1]) * b2f(d0[j + 1]));
            A1.u[j >> 1] = f2b2(b2f(s1[j]) * b2f(d1[j]), b2f(s1[j + 1]) * b2f(d1[j + 1]));
            A2.u[j >> 1] = 0u;
        }
        if (q == 0) {                        // k = 64..71 -> e_geo[e][0..7]
            f32x4 g0 = __builtin_nontemporal_load((const f32x4*)(egeo + (size_t)e * 8));
            f32x4 g1 = __builtin_nontemporal_load((const f32x4*)(egeo + (size_t)e * 8 + 4));
            A2.u[0] = f2b2(g0[0], g0[1]);
            A2.u[1] = f2b2(g0[2], g0[3]);
            A2.u[2] = f2b2(g1[0], g1[1]);
            A2.u[3] = f2b2(g1[2], g1[3]);
        }

        const float* gp = gamma + b * 64 + q * 4;
        const float* bp = beta2 + b * 64 + q * 4;
        float* op = out + (size_t)e * 64 + q * 4;

        #pragma unroll
        for (int t = 0; t < 4; ++t) {
            f32x4 c = {0.f, 0.f, 0.f, 0.f};
            // swapped operands -> C^T: rows=features t*16+q*4+i, cols=edges
            c = __builtin_amdgcn_mfma_f32_16x16x32_bf16(bfrag[0][t], A0.v, c, 0, 0, 0);
            c = __builtin_amdgcn_mfma_f32_16x16x32_bf16(bfrag[1][t], A1.v, c, 0, 0, 0);
            c = __builtin_amdgcn_mfma_f32_16x16x32_bf16(bfrag[2][t], A2.v, c, 0, 0, 0);

            f32x4 gm = *(const f32x4*)(gp + t * 16);
            f32x4 bt = *(const f32x4*)(bp + t * 16);
            f32x4 r;
            #pragma unroll
            for (int i = 0; i < 4; ++i) {
                float x = fmaf(c[i], gm[i], bt[i]);
                r[i] = x > 0.f ? x : 0.f;
            }
            __builtin_nontemporal_store(r, (f32x4*)(op + t * 16));
        }
    }
}

extern "C" void kernel_launch(void* const* d_in, const int* in_sizes, int n_in,
                              void* d_out, int out_size, void* d_ws, size_t ws_size,
                              hipStream_t stream) {
    const float* node_feats = (const float*)d_in[0];
    const int*   edge_index = (const int*)  d_in[1];
    const float* e_geo      = (const float*)d_in[2];
    const float* cond       = (const float*)d_in[3];
    const int*   ebatch     = (const int*)  d_in[4];
    const float* Wn         = (const float*)d_in[5];
    const float* bn         = (const float*)d_in[6];
    const float* Wg         = (const float*)d_in[7];
    const float* bg         = (const float*)d_in[8];
    const float* Wc         = (const float*)d_in[9];
    const float* bc         = (const float*)d_in[10];
    const float* Wx         = (const float*)d_in[11];
    float* out = (float*)d_out;

    char* ws = (char*)d_ws;
    float*          gamma  = (float*)(ws);                    // 16384 B
    float*          beta2  = (float*)(ws + 16384);            // 16384 B
    unsigned short* Bfrag  = (unsigned short*)(ws + 32768);   // 12288 B
    unsigned short* nprojb = (unsigned short*)(ws + 49152);   // 12.8 MB

    hipLaunchKernelGGL(prep_nproj_kernel, dim3(65 + 3125), dim3(256), 0, stream,
                       cond, Wc, bc, Wg, bg, Wx, node_feats, Wn, bn,
                       gamma, beta2, Bfrag, nprojb);
    hipLaunchKernelGGL(edge_kernel, dim3(6250), dim3(256), 0, stream,
                       nprojb, edge_index, e_geo, ebatch, Bfrag, gamma, beta2, out);
}